// Round 10
// baseline (286.111 us; speedup 1.0000x reference)
//
#include <hip/hip_runtime.h>
#include <hip/hip_bf16.h>
#include <stdint.h>

// ---------------- problem constants ----------------
#define BATCH   16384
#define SDIM    128
#define ENCK    10
#define ADIM    32
#define DECK    10
#define HID     2048
#define KSPINE  1280      // SDIM*ENCK

typedef __bf16 bf16x8 __attribute__((ext_vector_type(8)));
typedef float  f32x4  __attribute__((ext_vector_type(4)));
typedef unsigned short u16x8 __attribute__((ext_vector_type(8)));

typedef __attribute__((address_space(1))) const void kGlobalVoid;
typedef __attribute__((address_space(3))) void       kLdsVoid;

__device__ __forceinline__ unsigned short f2b(float f) {
  union { float f; unsigned u; } v; v.f = f;
  unsigned r = v.u + 0x7fffu + ((v.u >> 16) & 1u);   // RNE
  return (unsigned short)(r >> 16);
}

// ---------------- B pack: W[N,K] fp32 -> fragment-ordered bf16 ----------------
// Bpack unit u = ((ktb*128 + nt)*2 + ks)*64 + lane, 16B each:
//   col = nt*16 + (lane&15), kb = ktb*64 + ks*32 + (lane>>4)*8, 8 elems W[col][kb..+8].
// GEMM B-fragment load becomes ONE coalesced dwordx4 (1KB/wave).
__global__ void pack_kernel(const float* __restrict__ W, u16x8* __restrict__ out,
                            int K, int nunits) {
  int idx = blockIdx.x * 256 + threadIdx.x;
  if (idx >= nunits) return;
  int lane = idx & 63, ks = (idx >> 6) & 1, nt = (idx >> 7) & 127, ktb = idx >> 14;
  int col = nt * 16 + (lane & 15);
  int kb  = ktb * 64 + ks * 32 + (lane >> 4) * 8;
  const float* src = W + (size_t)col * K + kb;
  u16x8 o;
#pragma unroll
  for (int j = 0; j < 8; ++j) o[j] = f2b(src[j]);
  out[idx] = o;
}

// ---------------- encoder: sigmoid((x-mean)/std) -> bf16 spine ----------------
__global__ void encoder_kernel(const float* __restrict__ state,
                               const float* __restrict__ mean,
                               const float* __restrict__ stdv,
                               unsigned* __restrict__ spine) {
  int idx = blockIdx.x * blockDim.x + threadIdx.x;   // b*SDIM + d
  if (idx >= BATCH * SDIM) return;
  int d = idx & (SDIM - 1);
  float x = state[idx];
  float vals[ENCK];
#pragma unroll
  for (int k = 0; k < ENCK; ++k) {
    float z = (x - mean[d * ENCK + k]) / stdv[d * ENCK + k];
    vals[k] = 1.f / (1.f + __expf(-z));
  }
  unsigned* dst = spine + idx * (ENCK / 2);
#pragma unroll
  for (int k = 0; k < ENCK / 2; ++k)
    dst[k] = (unsigned)f2b(vals[2 * k]) | ((unsigned)f2b(vals[2 * k + 1]) << 16);
}

// ---------------- Weff/beff builders: fold grouped-conv into W3 ----------------
__global__ void weff_kernel(const float* __restrict__ W3, const float* __restrict__ Wd,
                            unsigned short* __restrict__ Weff) {
  int idx = blockIdx.x * 256 + threadIdx.x;   // a*2048 + j, 65536 total
  int a = idx >> 11, j = idx & 2047;
  float s = 0.f;
#pragma unroll
  for (int k = 0; k < DECK; ++k)
    s += Wd[a * DECK + k] * W3[(size_t)(a * DECK + k) * HID + j];
  Weff[idx] = f2b(s);
}

__global__ void beff_kernel(const float* __restrict__ b3, const float* __restrict__ Wd,
                            const float* __restrict__ bd, float* __restrict__ beff) {
  int a = threadIdx.x;
  if (a >= ADIM) return;
  float s = bd[a];
#pragma unroll
  for (int k = 0; k < DECK; ++k) s += Wd[a * DECK + k] * b3[a * DECK + k];
  beff[a] = s;
}

// ---------------- 256x256 bf16 GEMM: A via LDS (2x32KB), B coalesced global->reg ----------------
// 512 thr = 8 waves (2M x 4N), wave tile 128x64, 16x16x32 MFMA, acc[8][4].
// B never touches LDS: fragment-packed Bpack gives 1KB/wave coalesced dwordx4 loads,
// L2-resident (512KB k-slice shared by all blocks in lockstep).
// LDS/K64/CU: 128KB reads + 32KB writes (~1880cy) < MFMA floor (2064cy) -> MFMA-bound.
// Half (K-64) = 4 phases (phase = m-pair mp), shadow ds_reads for p+1 during p:
//  p0: {stage A-next(4 gload_lds) ; B-next(8 coalesced global)} ; MFMA mp0 ; shadow mp1
//  p1: MFMA mp1 ; shadow mp2
//  p2: MFMA mp2 ; vmcnt(8) retires staging (B loads newer, stay in flight) ; shadow mp3
//  p3: MFMA mp3 ; shadow mp0 from NEXT buffer (safe: staged p0, retired p2, barrier p2)
// Buffer overwrite at p0 is >=2 barriers after that buffer's last ds_read (prev half p2).
// B consumption wait: compiler-counted vmcnt (B is 1 half old ~3000cy -> no stall).

#define A0B 0
#define A1B 32768

#define FENCE asm volatile("" ::: "memory")
#define SB0 __builtin_amdgcn_sched_barrier(0)
#define BAR __builtin_amdgcn_s_barrier()
#define LGKM0 do { asm volatile("s_waitcnt lgkmcnt(0)" ::: "memory"); SB0; } while (0)
#define VM8 do { asm volatile("s_waitcnt vmcnt(8)" ::: "memory"); SB0; } while (0)

// stage one 32KB A half-buffer (256 rows x 64 bf16): 4 gload_lds x 512 thr x 16B
#define STAGE4(LDSB, KT)                                                                     \
  _Pragma("unroll")                                                                          \
  for (int g = 0; g < 4; ++g) {                                                              \
    __builtin_amdgcn_global_load_lds(                                                        \
        (kGlobalVoid*)(A + (size_t)(row0 + g * 64 + rs) * K + (KT) + ce),                    \
        (kLdsVoid*)(smem + (LDSB) + g * 8192 + t * 16), 16, 0, 0);                           \
  }

// B fragments for one K-64 half from packed layout (8 coalesced 16B loads)
#define GLB_BF(DST, KTB)                                                                     \
  _Pragma("unroll")                                                                          \
  for (int n = 0; n < 4; ++n) {                                                              \
    _Pragma("unroll")                                                                        \
    for (int ks = 0; ks < 2; ++ks) {                                                         \
      DST[n][ks] = *reinterpret_cast<const bf16x8*>(                                         \
          Bwave + (size_t)(KTB) * 262144 + (n * 2 + ks) * 1024);                             \
    }                                                                                        \
  }

#define DS_AF(DST, ABASE, MPN)                                                               \
  _Pragma("unroll")                                                                          \
  for (int j2 = 0; j2 < 2; ++j2) {                                                           \
    _Pragma("unroll")                                                                        \
    for (int ks = 0; ks < 2; ++ks) {                                                         \
      int rowl = wr * 128 + (MPN) * 32 + j2 * 16 + lr;                                       \
      DST[j2][ks] = *reinterpret_cast<const bf16x8*>(                                        \
          smem + (ABASE) + rowl * 128 + ((((ks) << 6) | (kh << 4)) ^ swz));                  \
    }                                                                                        \
  }

#define MFMA16(MP, AF, BF)                                                                   \
  _Pragma("unroll")                                                                          \
  for (int j2 = 0; j2 < 2; ++j2)                                                             \
    _Pragma("unroll")                                                                        \
    for (int n = 0; n < 4; ++n)                                                              \
      _Pragma("unroll")                                                                      \
      for (int ks = 0; ks < 2; ++ks)                                                         \
        acc[(MP) * 2 + j2][n] = __builtin_amdgcn_mfma_f32_16x16x32_bf16(                     \
            AF[j2][ks], BF[n][ks], acc[(MP) * 2 + j2][n], 0, 0, 0);

// one K-64 half: cur A buffer CURB (+bfc=BF_C), prefetch NXTB<-KTN and BF_N<-KTBN
#define HALF(CURB, NXTB, BF_C, BF_N, KTN, KTBN)                                              \
  do {                                                                                       \
    /* p0 */                                                                                 \
    LGKM0;                                                                                   \
    STAGE4(NXTB, KTN);                                                                       \
    SB0;                                                                                     \
    GLB_BF(BF_N, KTBN);                                                                      \
    SB0;                                                                                     \
    __builtin_amdgcn_s_setprio(1); MFMA16(0, afc, BF_C); __builtin_amdgcn_s_setprio(0);      \
    DS_AF(afn, CURB, 1);                                                                     \
    FENCE; BAR;                                                                              \
    /* p1 */                                                                                 \
    LGKM0;                                                                                   \
    __builtin_amdgcn_s_setprio(1); MFMA16(1, afn, BF_C); __builtin_amdgcn_s_setprio(0);      \
    DS_AF(afc, CURB, 2);                                                                     \
    FENCE; BAR;                                                                              \
    /* p2 */                                                                                 \
    LGKM0;                                                                                   \
    __builtin_amdgcn_s_setprio(1); MFMA16(2, afc, BF_C); __builtin_amdgcn_s_setprio(0);      \
    VM8;                                                                                     \
    DS_AF(afn, CURB, 3);                                                                     \
    FENCE; BAR;                                                                              \
    /* p3 */                                                                                 \
    LGKM0;                                                                                   \
    __builtin_amdgcn_s_setprio(1); MFMA16(3, afn, BF_C); __builtin_amdgcn_s_setprio(0);      \
    DS_AF(afc, NXTB, 0);                                                                     \
    FENCE; BAR;                                                                              \
  } while (0)

__global__ __launch_bounds__(512, 2) void gemm256(
    const unsigned short* __restrict__ A,    // [M,K] bf16
    const char* __restrict__ Bp,             // Bpack (fragment-ordered bf16)
    const float* __restrict__ bias,          // [2048]
    unsigned short* __restrict__ Cout,       // [M,2048] bf16
    int K, int NI2) {                        // NI2 = K/128
  __shared__ char smem[65536];

  const int t    = threadIdx.x;
  const int lane = t & 63;
  const int w    = t >> 6;
  const int wr   = w >> 2;      // 0..1
  const int wc   = w & 3;       // 0..3
  const int lr   = lane & 15;
  const int kh   = lane >> 4;   // 0..3
  const int swz  = (lr & 7) << 4;
  const int rs   = t >> 3;                      // stage row within 64-row band
  const int ce   = ((t & 7) ^ (rs & 7)) << 3;   // inverse-swizzled col (elements)

  // XCD-aware mapping: XCD owns an M-band x all 8 N-blocks (A fetched once per chip).
  const int bid = blockIdx.x;
  const int xcd = bid & 7, idx = bid >> 3;           // idx in [0,64)
  const int row0 = (xcd * 8 + (idx >> 3)) * 256;
  const int col0 = (idx & 7) * 256;

  // per-wave B base in packed layout: nt0 = col/16 for this wave's first n-frag
  const char* Bwave = Bp + ((size_t)(((col0 >> 4) + wc * 4) * 2 * 64) + lane) * 16;

  f32x4 acc[8][4];
#pragma unroll
  for (int m = 0; m < 8; ++m)
#pragma unroll
    for (int n = 0; n < 4; ++n)
      acc[m][n] = (f32x4){0.f, 0.f, 0.f, 0.f};

  bf16x8 afc[2][2], afn[2][2], bfc[4][2], bfn[4][2];

  // ---- prologue: A h0 -> buf0 (4 stages), B h0 -> bfc (8 loads, stay in flight) ----
  STAGE4(A0B, 0);
  SB0;
  GLB_BF(bfc, 0);
  SB0;
  VM8;                 // retire the 4 staging loads; B (8) still outstanding
  FENCE;
  BAR;
  DS_AF(afc, A0B, 0);

  for (int i = 0; i < NI2; ++i) {
    int kt0 = i << 7;
    int kt1 = kt0 + 64;                             // always < K
    int kt2 = kt0 + 128; if (kt2 >= K) kt2 = 0;     // wrapped on last iter (data unused)

    HALF(A0B, A1B, bfc, bfn, kt1, kt1 >> 6);
    HALF(A1B, A0B, bfn, bfc, kt2, kt2 >> 6);
  }

  // ---- epilogue: bias + relu + bf16 store ----
#pragma unroll
  for (int m = 0; m < 8; ++m) {
    int gr0 = row0 + wr * 128 + m * 16 + kh * 4;
#pragma unroll
    for (int n = 0; n < 4; ++n) {
      int gc = col0 + wc * 64 + n * 16 + lr;
      float bv = bias[gc];
#pragma unroll
      for (int v = 0; v < 4; ++v) {
        float val = fmaxf(acc[m][n][v] + bv, 0.f);
        Cout[(size_t)(gr0 + v) * 2048 + gc] = f2b(val);
      }
    }
  }
}

// ---------------- skinny GEMM3 + tanh: [16384,2048]x[32,2048]^T -> d_out ----------------
__global__ __launch_bounds__(128) void gemm_skinny(
    const unsigned short* __restrict__ A,    // h2 [16384,2048] bf16
    const unsigned short* __restrict__ Bw,   // Weff [32,2048] bf16
    const float* __restrict__ beff,          // [32]
    float* __restrict__ out) {               // [16384,32] fp32
  const int t = threadIdx.x, lane = t & 63, w = t >> 6;
  const int lr = lane & 15, kh = lane >> 4;
  const int row0 = (blockIdx.x * 2 + w) * 16;
  f32x4 acc[2];
  acc[0] = (f32x4){0.f, 0.f, 0.f, 0.f};
  acc[1] = (f32x4){0.f, 0.f, 0.f, 0.f};

  const unsigned short* Arow = A  + (size_t)(row0 + lr) * HID + kh * 8;
  const unsigned short* B0   = Bw + (size_t)(lr) * HID + kh * 8;
  const unsigned short* B1   = Bw + (size_t)(16 + lr) * HID + kh * 8;

#pragma unroll 4
  for (int kt = 0; kt < HID; kt += 32) {
    bf16x8 a  = *reinterpret_cast<const bf16x8*>(Arow + kt);
    bf16x8 b0 = *reinterpret_cast<const bf16x8*>(B0 + kt);
    bf16x8 b1 = *reinterpret_cast<const bf16x8*>(B1 + kt);
    acc[0] = __builtin_amdgcn_mfma_f32_16x16x32_bf16(a, b0, acc[0], 0, 0, 0);
    acc[1] = __builtin_amdgcn_mfma_f32_16x16x32_bf16(a, b1, acc[1], 0, 0, 0);
  }
#pragma unroll
  for (int n = 0; n < 2; ++n)
#pragma unroll
    for (int v = 0; v < 4; ++v) {
      int row = row0 + kh * 4 + v;
      int col = n * 16 + lr;
      out[(size_t)row * ADIM + col] = tanhf(acc[n][v] + beff[col]);
    }
}

// ---------------- launch ----------------
extern "C" void kernel_launch(void* const* d_in, const int* in_sizes, int n_in,
                              void* d_out, int out_size, void* d_ws, size_t ws_size,
                              hipStream_t stream) {
  const float* state    = (const float*)d_in[0];
  const float* mean_enc = (const float*)d_in[1];
  const float* std_enc  = (const float*)d_in[2];
  const float* W1 = (const float*)d_in[3];
  const float* b1 = (const float*)d_in[4];
  const float* W2 = (const float*)d_in[5];
  const float* b2 = (const float*)d_in[6];
  const float* W3 = (const float*)d_in[7];
  const float* b3 = (const float*)d_in[8];
  const float* Wd = (const float*)d_in[9];
  const float* bd = (const float*)d_in[10];

  char* ws = (char*)d_ws;
  char*           W1p   = ws + 0;                              //  5,242,880 (20*128*2*64*16)
  char*           W2p   = ws + 5242880;                        //  8,388,608 (32*128*2*64*16)
  unsigned short* Weff  = (unsigned short*)(ws + 13631488);    //    131,072
  float*          beff  = (float*)(ws + 13762560);             //        128
  unsigned short* spine = (unsigned short*)(ws + 13762688);    // 41,943,040
  unsigned short* h1    = (unsigned short*)(ws + 55705728);    // 67,108,864
  unsigned short* h2    = (unsigned short*)(ws + 122814592);   // 67,108,864 -> end ~190MB

  // weight preprocessing: fragment-order pack (replaces plain f2b)
  pack_kernel<<<1280, 256, 0, stream>>>(W1, (u16x8*)W1p, KSPINE, 327680);
  pack_kernel<<<2048, 256, 0, stream>>>(W2, (u16x8*)W2p, HID,    524288);
  weff_kernel<<<256, 256, 0, stream>>>(W3, Wd, Weff);
  beff_kernel<<<1, 64, 0, stream>>>(b3, Wd, bd, beff);

  // encoder
  encoder_kernel<<<(BATCH * SDIM) / 256, 256, 0, stream>>>(state, mean_enc, std_enc, (unsigned*)spine);

  // GEMM chain
  gemm256<<<512, 512, 0, stream>>>(spine, W1p, b1, h1, KSPINE, KSPINE / 128);
  gemm256<<<512, 512, 0, stream>>>(h1,    W2p, b2, h2, HID,    HID / 128);
  gemm_skinny<<<BATCH / 32, 128, 0, stream>>>(h2, Weff, beff, (float*)d_out);
}

// Round 11
// 249.852 us; speedup vs baseline: 1.1451x; 1.1451x over previous
//
#include <hip/hip_runtime.h>
#include <hip/hip_bf16.h>
#include <stdint.h>

// ---------------- problem constants ----------------
#define BATCH   16384
#define SDIM    128
#define ENCK    10
#define ADIM    32
#define DECK    10
#define HID     2048
#define KSPINE  1280      // SDIM*ENCK

typedef __bf16 bf16x8 __attribute__((ext_vector_type(8)));
typedef float  f32x4  __attribute__((ext_vector_type(4)));

typedef __attribute__((address_space(1))) const void kGlobalVoid;
typedef __attribute__((address_space(3))) void       kLdsVoid;

__device__ __forceinline__ unsigned short f2b(float f) {
  union { float f; unsigned u; } v; v.f = f;
  unsigned r = v.u + 0x7fffu + ((v.u >> 16) & 1u);   // RNE
  return (unsigned short)(r >> 16);
}

// ---------------- fp32 -> bf16 convert (2 elems/thread) ----------------
__global__ void f2b_kernel(const float* __restrict__ in, unsigned* __restrict__ out, int n2) {
  int i = blockIdx.x * blockDim.x + threadIdx.x;
  if (i >= n2) return;
  float2 v = reinterpret_cast<const float2*>(in)[i];
  out[i] = (unsigned)f2b(v.x) | ((unsigned)f2b(v.y) << 16);
}

// ---------------- encoder v2: one thread per (b,d,k-pair) -> coalesced dword write ----
// idx = (b*128+d)*5 + kk ; state idx = idx/5 ; out dword = spine_u32[idx].
// Loads: state broadcast (5 lanes share), mean/std stride-8B coalesced; 2 sigmoids/thread.
__global__ __launch_bounds__(256) void encoder_kernel(const float* __restrict__ state,
                               const float* __restrict__ mean,
                               const float* __restrict__ stdv,
                               unsigned* __restrict__ spine) {
  int idx = blockIdx.x * 256 + threadIdx.x;          // < BATCH*SDIM*5
  int idx1 = (int)(((long long)idx * 0x66666667LL) >> 33);  // idx/5 (magic)
  int kk = idx - idx1 * 5;                           // k-pair 0..4
  int d  = idx1 & (SDIM - 1);
  float x = state[idx1];
  int mi = d * ENCK + kk * 2;
  float m0 = mean[mi], m1 = mean[mi + 1];
  float s0 = stdv[mi], s1 = stdv[mi + 1];
  float v0 = 1.f / (1.f + __expf((m0 - x) / s0));
  float v1 = 1.f / (1.f + __expf((m1 - x) / s1));
  spine[idx] = (unsigned)f2b(v0) | ((unsigned)f2b(v1) << 16);
}

// ---------------- Weff/beff builders: fold grouped-conv into W3 ----------------
__global__ void weff_kernel(const float* __restrict__ W3, const float* __restrict__ Wd,
                            unsigned short* __restrict__ Weff) {
  int idx = blockIdx.x * 256 + threadIdx.x;   // a*2048 + j, 65536 total
  int a = idx >> 11, j = idx & 2047;
  float s = 0.f;
#pragma unroll
  for (int k = 0; k < DECK; ++k)
    s += Wd[a * DECK + k] * W3[(size_t)(a * DECK + k) * HID + j];
  Weff[idx] = f2b(s);
}

__global__ void beff_kernel(const float* __restrict__ b3, const float* __restrict__ Wd,
                            const float* __restrict__ bd, float* __restrict__ beff) {
  int a = threadIdx.x;
  if (a >= ADIM) return;
  float s = bd[a];
#pragma unroll
  for (int k = 0; k < DECK; ++k) s += Wd[a * DECK + k] * b3[a * DECK + k];
  beff[a] = s;
}

// ---------------- 256x256 8-phase bf16 GEMM (R7: balanced B reads + T19) ----------------
// Best measured structure: GEMM2 112us / 1225 TF, MfmaUtil 53, bank-conflict 0.

#define A0B 0
#define B0B 32768
#define A1B 65536
#define B1B 98304

#define FENCE asm volatile("" ::: "memory")

#define STAGE(BASEPTR, R0A, R0B, LDS0, LDS1, KT)                                             \
  __builtin_amdgcn_global_load_lds((kGlobalVoid*)((BASEPTR) + (size_t)((R0A) + rs) * K + (KT) + ce), \
                                   (kLdsVoid*)(smem + (LDS0) + t * 16), 16, 0, 0);           \
  __builtin_amdgcn_global_load_lds((kGlobalVoid*)((BASEPTR) + (size_t)((R0B) + rs) * K + (KT) + ce), \
                                   (kLdsVoid*)(smem + (LDS1) + t * 16), 16, 0, 0);

#define DS_AF(DST, ABASE, MPN)                                                               \
  _Pragma("unroll")                                                                          \
  for (int j2 = 0; j2 < 2; ++j2) {                                                           \
    _Pragma("unroll")                                                                        \
    for (int ks = 0; ks < 2; ++ks) {                                                         \
      int rowl = wr * 128 + (MPN) * 32 + j2 * 16 + lr;                                       \
      DST[j2][ks] = *reinterpret_cast<const bf16x8*>(                                        \
          smem + (ABASE) + rowl * 128 + ((((ks) << 6) | (kh << 4)) ^ swz));                  \
    }                                                                                        \
  }

// read B frag pair n=NP (both ks) for the NEXT half
#define DS_B2(DST, NP, BBASE)                                                                \
  _Pragma("unroll")                                                                          \
  for (int ks = 0; ks < 2; ++ks) {                                                           \
    int rowl = wc * 64 + (NP) * 16 + lr;                                                     \
    DST[NP][ks] = *reinterpret_cast<const bf16x8*>(                                          \
        smem + (BBASE) + rowl * 128 + ((((ks) << 6) | (kh << 4)) ^ swz));                    \
  }

// all 8 B frags (prologue only)
#define DS_BF(DST, BBASE)                                                                    \
  _Pragma("unroll")                                                                          \
  for (int n = 0; n < 4; ++n) {                                                              \
    _Pragma("unroll")                                                                        \
    for (int ks = 0; ks < 2; ++ks) {                                                         \
      int rowl = wc * 64 + n * 16 + lr;                                                      \
      DST[n][ks] = *reinterpret_cast<const bf16x8*>(                                         \
          smem + (BBASE) + rowl * 128 + ((((ks) << 6) | (kh << 4)) ^ swz));                  \
    }                                                                                        \
  }

#define MFMA16(MP, AF, BF)                                                                   \
  _Pragma("unroll")                                                                          \
  for (int j2 = 0; j2 < 2; ++j2)                                                             \
    _Pragma("unroll")                                                                        \
    for (int n = 0; n < 4; ++n)                                                              \
      _Pragma("unroll")                                                                      \
      for (int ks = 0; ks < 2; ++ks)                                                         \
        acc[(MP) * 2 + j2][n] = __builtin_amdgcn_mfma_f32_16x16x32_bf16(                     \
            AF[j2][ks], BF[n][ks], acc[(MP) * 2 + j2][n], 0, 0, 0);

// T19: interleave 16 MFMA with 6 ds_reads + 2 gload_lds inside the phase region
#define SGB_PHASE                                                                            \
  __builtin_amdgcn_sched_group_barrier(0x8, 2, 0);                                           \
  __builtin_amdgcn_sched_group_barrier(0x100, 1, 0);                                         \
  __builtin_amdgcn_sched_group_barrier(0x8, 2, 0);                                           \
  __builtin_amdgcn_sched_group_barrier(0x100, 1, 0);                                         \
  __builtin_amdgcn_sched_group_barrier(0x20, 2, 0);                                          \
  __builtin_amdgcn_sched_group_barrier(0x8, 3, 0);                                           \
  __builtin_amdgcn_sched_group_barrier(0x100, 1, 0);                                         \
  __builtin_amdgcn_sched_group_barrier(0x8, 3, 0);                                           \
  __builtin_amdgcn_sched_group_barrier(0x100, 1, 0);                                         \
  __builtin_amdgcn_sched_group_barrier(0x8, 3, 0);                                           \
  __builtin_amdgcn_sched_group_barrier(0x100, 1, 0);                                         \
  __builtin_amdgcn_sched_group_barrier(0x8, 3, 0);                                           \
  __builtin_amdgcn_sched_group_barrier(0x100, 1, 0);

#define VM_NONE
#define VM2 asm volatile("s_waitcnt vmcnt(2)" ::: "memory"); __builtin_amdgcn_sched_barrier(0);
#define VM6 asm volatile("s_waitcnt vmcnt(6)" ::: "memory"); __builtin_amdgcn_sched_barrier(0);

#define PH(MP, AF_C, AF_N, BF_C, BF_N, NXT_A, NXT_MP, BBASE_N, VMW, STG)                     \
  do {                                                                                       \
    asm volatile("s_waitcnt lgkmcnt(0)" ::: "memory");                                       \
    __builtin_amdgcn_sched_barrier(0);                                                       \
    VMW                                                                                      \
    __builtin_amdgcn_s_setprio(1);                                                           \
    MFMA16(MP, AF_C, BF_C);                                                                  \
    __builtin_amdgcn_s_setprio(0);                                                           \
    DS_AF(AF_N, NXT_A, NXT_MP);                                                              \
    DS_B2(BF_N, MP, BBASE_N);                                                                \
    STG;                                                                                     \
    SGB_PHASE;                                                                               \
    FENCE;                                                                                   \
    __builtin_amdgcn_s_barrier();                                                            \
  } while (0)

__global__ __launch_bounds__(512, 2) void gemm256(
    const unsigned short* __restrict__ A,    // [M,K] bf16
    const unsigned short* __restrict__ Bw,   // [2048,K] bf16
    const float* __restrict__ bias,          // [2048]
    unsigned short* __restrict__ Cout,       // [M,2048] bf16
    int K, int NI) {                         // NI = K/128
  __shared__ char smem[131072];

  const int t    = threadIdx.x;
  const int lane = t & 63;
  const int w    = t >> 6;
  const int wr   = w >> 2;      // 0..1
  const int wc   = w & 3;       // 0..3
  const int lr   = lane & 15;
  const int kh   = lane >> 4;   // 0..3
  const int swz  = (lr & 7) << 4;
  const int rs   = t >> 3;                      // stage row within 64-row band
  const int ce   = ((t & 7) ^ (rs & 7)) << 3;   // inverse-swizzled col (elements)

  // XCD-aware mapping: XCD owns an M-band x all 8 N-blocks (A fetched once per chip).
  const int bid = blockIdx.x;
  const int xcd = bid & 7, idx = bid >> 3;           // idx in [0,64)
  const int row0 = (xcd * 8 + (idx >> 3)) * 256;
  const int col0 = (idx & 7) * 256;

  f32x4 acc[8][4];
#pragma unroll
  for (int m = 0; m < 8; ++m)
#pragma unroll
    for (int n = 0; n < 4; ++n)
      acc[m][n] = (f32x4){0.f, 0.f, 0.f, 0.f};

  bf16x8 afc[2][2], afn[2][2], bfA[4][2], bfB[4][2];

  // ---- prologue: B0<-k0..63, A0<-k0..127, B1<-k64..127, A1 q0q2<-k64 ----
  STAGE(Bw, col0 + 0,   col0 + 64,  B0B + 0,     B0B + 8192,  0);
  STAGE(Bw, col0 + 128, col0 + 192, B0B + 16384, B0B + 24576, 0);
  STAGE(A,  row0 + 0,   row0 + 128, A0B + 0,     A0B + 16384, 0);
  STAGE(A,  row0 + 64,  row0 + 192, A0B + 8192,  A0B + 24576, 0);
  STAGE(Bw, col0 + 0,   col0 + 64,  B1B + 0,     B1B + 8192,  64);
  STAGE(Bw, col0 + 128, col0 + 192, B1B + 16384, B1B + 24576, 64);
  STAGE(A,  row0 + 0,   row0 + 128, A1B + 0,     A1B + 16384, 64);
  asm volatile("s_waitcnt vmcnt(0)" ::: "memory");
  FENCE;
  __builtin_amdgcn_s_barrier();
  DS_AF(afc, A0B, 0);     // mp0 for p0
  DS_BF(bfA, B0B);        // full B for half0 (B0B overwritten from p1 on)

  for (int i = 0; i < NI; ++i) {
    int kt0 = i << 7;
    int kt1 = kt0 + 64;
    int kt2 = kt0 + 128; if (kt2 >= K) kt2 -= K;   // wrapped on last iter (data unused)
    int kt3 = kt0 + 192; if (kt3 >= K) kt3 -= K;

    // half0: A0B + bfA ; prefetch bfB from B1B, A shadow, stages
    PH(0, afc, afn, bfA, bfB, A0B, 1, B1B, VM2,
       STAGE(A,  row0 + 64,  row0 + 192, A1B + 8192,  A1B + 24576, kt1));
    PH(1, afn, afc, bfA, bfB, A0B, 2, B1B, VM_NONE,
       STAGE(Bw, col0 + 0,   col0 + 64,  B0B + 0,     B0B + 8192,  kt2));
    PH(2, afc, afn, bfA, bfB, A0B, 3, B1B, VM_NONE,
       STAGE(Bw, col0 + 128, col0 + 192, B0B + 16384, B0B + 24576, kt2));
    PH(3, afn, afc, bfA, bfB, A1B, 0, B1B, VM6,
       STAGE(A,  row0 + 0,   row0 + 128, A0B + 0,     A0B + 16384, kt2));
    // half1: A1B + bfB ; prefetch bfA (next iter) from B0B
    PH(0, afc, afn, bfB, bfA, A1B, 1, B0B, VM2,
       STAGE(A,  row0 + 64,  row0 + 192, A0B + 8192,  A0B + 24576, kt2));
    PH(1, afn, afc, bfB, bfA, A1B, 2, B0B, VM_NONE,
       STAGE(Bw, col0 + 0,   col0 + 64,  B1B + 0,     B1B + 8192,  kt3));
    PH(2, afc, afn, bfB, bfA, A1B, 3, B0B, VM_NONE,
       STAGE(Bw, col0 + 128, col0 + 192, B1B + 16384, B1B + 24576, kt3));
    PH(3, afn, afc, bfB, bfA, A0B, 0, B0B, VM6,
       STAGE(A,  row0 + 0,   row0 + 128, A1B + 0,     A1B + 16384, kt3));
  }

  // ---- epilogue: bias + relu + bf16 store ----
#pragma unroll
  for (int m = 0; m < 8; ++m) {
    int gr0 = row0 + wr * 128 + m * 16 + kh * 4;
#pragma unroll
    for (int n = 0; n < 4; ++n) {
      int gc = col0 + wc * 64 + n * 16 + lr;
      float bv = bias[gc];
#pragma unroll
      for (int v = 0; v < 4; ++v) {
        float val = fmaxf(acc[m][n][v] + bv, 0.f);
        Cout[(size_t)(gr0 + v) * 2048 + gc] = f2b(val);
      }
    }
  }
}

// ---------------- skinny GEMM3 + tanh, split-K x4: [16384,2048]x[32,2048]^T ----------------
// 1024 blocks x 256 thr (4 waves). Wave w computes rows [blk*16,+16) over K-quarter w.
// Waves 1-3 dump partial acc to LDS; wave 0 reduces, adds beff, tanh, stores.
__global__ __launch_bounds__(256) void gemm_skinny(
    const unsigned short* __restrict__ A,    // h2 [16384,2048] bf16
    const unsigned short* __restrict__ Bw,   // Weff [32,2048] bf16
    const float* __restrict__ beff,          // [32]
    float* __restrict__ out) {               // [16384,32] fp32
  __shared__ char red[6144];                 // 3 waves x 64 lanes x 32B
  const int t = threadIdx.x, lane = t & 63, w = t >> 6;
  const int lr = lane & 15, kh = lane >> 4;
  const int row0 = blockIdx.x * 16;
  const int kb = w * (HID / 4);              // K-quarter base
  f32x4 acc[2];
  acc[0] = (f32x4){0.f, 0.f, 0.f, 0.f};
  acc[1] = (f32x4){0.f, 0.f, 0.f, 0.f};

  const unsigned short* Arow = A  + (size_t)(row0 + lr) * HID + kb + kh * 8;
  const unsigned short* B0   = Bw + (size_t)(lr) * HID + kb + kh * 8;
  const unsigned short* B1   = Bw + (size_t)(16 + lr) * HID + kb + kh * 8;

#pragma unroll 4
  for (int kt = 0; kt < HID / 4; kt += 32) {
    bf16x8 a  = *reinterpret_cast<const bf16x8*>(Arow + kt);
    bf16x8 b0 = *reinterpret_cast<const bf16x8*>(B0 + kt);
    bf16x8 b1 = *reinterpret_cast<const bf16x8*>(B1 + kt);
    acc[0] = __builtin_amdgcn_mfma_f32_16x16x32_bf16(a, b0, acc[0], 0, 0, 0);
    acc[1] = __builtin_amdgcn_mfma_f32_16x16x32_bf16(a, b1, acc[1], 0, 0, 0);
  }

  if (w) {
    char* p = red + (w - 1) * 2048 + lane * 32;
    *reinterpret_cast<f32x4*>(p)      = acc[0];
    *reinterpret_cast<f32x4*>(p + 16) = acc[1];
  }
  __syncthreads();
  if (w == 0) {
#pragma unroll
    for (int j = 0; j < 3; ++j) {
      char* p = red + j * 2048 + lane * 32;
      acc[0] += *reinterpret_cast<const f32x4*>(p);
      acc[1] += *reinterpret_cast<const f32x4*>(p + 16);
    }
#pragma unroll
    for (int n = 0; n < 2; ++n)
#pragma unroll
      for (int v = 0; v < 4; ++v) {
        int row = row0 + kh * 4 + v;
        int col = n * 16 + lr;
        out[(size_t)row * ADIM + col] = tanhf(acc[n][v] + beff[col]);
      }
  }
}

// ---------------- launch ----------------
extern "C" void kernel_launch(void* const* d_in, const int* in_sizes, int n_in,
                              void* d_out, int out_size, void* d_ws, size_t ws_size,
                              hipStream_t stream) {
  const float* state    = (const float*)d_in[0];
  const float* mean_enc = (const float*)d_in[1];
  const float* std_enc  = (const float*)d_in[2];
  const float* W1 = (const float*)d_in[3];
  const float* b1 = (const float*)d_in[4];
  const float* W2 = (const float*)d_in[5];
  const float* b2 = (const float*)d_in[6];
  const float* W3 = (const float*)d_in[7];
  const float* b3 = (const float*)d_in[8];
  const float* Wd = (const float*)d_in[9];
  const float* bd = (const float*)d_in[10];

  char* ws = (char*)d_ws;
  unsigned short* W1b   = (unsigned short*)(ws + 0);           //  5,242,880
  unsigned short* W2b   = (unsigned short*)(ws + 5242880);     //  8,388,608
  unsigned short* Weff  = (unsigned short*)(ws + 13631488);    //    131,072
  float*          beff  = (float*)(ws + 13762560);             //        128
  unsigned short* spine = (unsigned short*)(ws + 13762688);    // 41,943,040
  unsigned short* h1    = (unsigned short*)(ws + 55705728);    // 67,108,864
  unsigned short* h2    = (unsigned short*)(ws + 122814592);   // 67,108,864 -> end ~190MB

  // weight preprocessing
  f2b_kernel<<<5120, 256, 0, stream>>>(W1, (unsigned*)W1b, 1310720);
  f2b_kernel<<<8192, 256, 0, stream>>>(W2, (unsigned*)W2b, 2097152);
  weff_kernel<<<256, 256, 0, stream>>>(W3, Wd, Weff);
  beff_kernel<<<1, 64, 0, stream>>>(b3, Wd, bd, beff);

  // encoder (BATCH*SDIM*5 threads, one dword each)
  encoder_kernel<<<(BATCH * SDIM * 5) / 256, 256, 0, stream>>>(state, mean_enc, std_enc, (unsigned*)spine);

  // GEMM chain
  gemm256<<<512, 512, 0, stream>>>(spine, W1b, b1, h1, KSPINE, KSPINE / 128);
  gemm256<<<512, 512, 0, stream>>>(h1,    W2b, b2, h2, HID,    HID / 128);
  gemm_skinny<<<BATCH / 16, 256, 0, stream>>>(h2, Weff, beff, (float*)d_out);
}